// Round 9
// baseline (236.531 us; speedup 1.0000x reference)
//
#include <hip/hip_runtime.h>
#include <hip/hip_bf16.h>

#define B_SZ 8
#define LSEQ 200
#define DMODEL 256
#define DINNER 512
#define DSTATE 64
#define DTRANK 16
#define ROWS (B_SZ * LSEQ)   // 1600

using bf16x8 = __attribute__((ext_vector_type(8))) short;
using f32x4  = __attribute__((ext_vector_type(4))) float;

__device__ __forceinline__ float softplusf(float x) {
    return (x > 20.f) ? x : log1pf(__expf(x));
}
__device__ __forceinline__ float siluf(float x) {
    return x / (1.f + __expf(-x));
}
__device__ __forceinline__ unsigned short f2bf(float f) {
    union { float f; unsigned int u; } v; v.f = f;
    unsigned int r = v.u + 0x7FFF + ((v.u >> 16) & 1);   // RNE
    return (unsigned short)(r >> 16);
}
__device__ __forceinline__ float bf2f(unsigned short u) {
    union { unsigned int i; float f; } v;
    v.i = ((unsigned int)u) << 16;
    return v.f;
}

// ---------------------------------------------------------------------------
// Shared MFMA inner loop + epilogue (all gemms use 64x64 tile, 4 waves 32x32,
// BK=32, split-bf16 hi*hi + hi*lo + lo*hi).
// ---------------------------------------------------------------------------
#define GEMM_FRAG_COMPUTE()                                                    \
    do {                                                                       \
        bf16x8 a_h[2], a_l[2], b_h[2], b_l[2];                                 \
        _Pragma("unroll")                                                      \
        for (int mi = 0; mi < 2; mi++) {                                       \
            int row = wm + mi * 16 + fr;                                       \
            a_h[mi] = *(const bf16x8*)&As_hi[row * 40 + fq * 8];               \
            a_l[mi] = *(const bf16x8*)&As_lo[row * 40 + fq * 8];               \
        }                                                                      \
        _Pragma("unroll")                                                      \
        for (int ni = 0; ni < 2; ni++) {                                       \
            int row = wn + ni * 16 + fr;                                       \
            b_h[ni] = *(const bf16x8*)&Bs_hi[row * 40 + fq * 8];               \
            b_l[ni] = *(const bf16x8*)&Bs_lo[row * 40 + fq * 8];               \
        }                                                                      \
        _Pragma("unroll")                                                      \
        for (int mi = 0; mi < 2; mi++)                                         \
            _Pragma("unroll")                                                  \
            for (int ni = 0; ni < 2; ni++) {                                   \
                acc[mi][ni] = __builtin_amdgcn_mfma_f32_16x16x32_bf16(a_h[mi], b_h[ni], acc[mi][ni], 0, 0, 0); \
                acc[mi][ni] = __builtin_amdgcn_mfma_f32_16x16x32_bf16(a_h[mi], b_l[ni], acc[mi][ni], 0, 0, 0); \
                acc[mi][ni] = __builtin_amdgcn_mfma_f32_16x16x32_bf16(a_l[mi], b_h[ni], acc[mi][ni], 0, 0, 0); \
            }                                                                  \
    } while (0)

// ---------------------------------------------------------------------------
// gemm1: xz = x[1600,256] @ W_in[256,1024].  A fp32 (split in staging),
// B = W_in fp32 read directly with transpose+split in staging.
// ---------------------------------------------------------------------------
__global__ __launch_bounds__(256) void gemm1_k(
    const float* __restrict__ A, const float* __restrict__ Wf,
    float* __restrict__ C)
{
    const int M = ROWS, N = 1024, K = 256;
    __shared__ unsigned short As_hi[64 * 40], As_lo[64 * 40];
    __shared__ unsigned short Bs_hi[64 * 40], Bs_lo[64 * 40];

    const int t    = threadIdx.x;
    const int m0   = blockIdx.y * 64;
    const int n0   = blockIdx.x * 64;
    const int lane = t & 63;
    const int w    = t >> 6;
    const int wm   = (w >> 1) * 32;
    const int wn   = (w & 1) * 32;
    const int fr   = lane & 15;
    const int fq   = lane >> 4;

    const int sr = t >> 2, sc = (t & 3) * 8;     // A staging
    const int kr = t >> 3, nc = (t & 7) * 8;     // B staging (transpose)

    f32x4 acc[2][2] = {};

    for (int k0 = 0; k0 < K; k0 += 32) {
        float4 a0 = *(const float4*)(A + (size_t)(m0 + sr) * K + k0 + sc);
        float4 a1 = *(const float4*)(A + (size_t)(m0 + sr) * K + k0 + sc + 4);
        float4 w0 = *(const float4*)(Wf + (size_t)(k0 + kr) * N + n0 + nc);
        float4 w1 = *(const float4*)(Wf + (size_t)(k0 + kr) * N + n0 + nc + 4);

        float av[8] = {a0.x, a0.y, a0.z, a0.w, a1.x, a1.y, a1.z, a1.w};
        float wv[8] = {w0.x, w0.y, w0.z, w0.w, w1.x, w1.y, w1.z, w1.w};
        union { unsigned short us[8]; int4 v; } uh, ul;
        unsigned short bh[8], bl[8];
#pragma unroll
        for (int j = 0; j < 8; j++) {
            unsigned short h = f2bf(av[j]);
            uh.us[j] = h; ul.us[j] = f2bf(av[j] - bf2f(h));
            unsigned short g = f2bf(wv[j]);
            bh[j] = g; bl[j] = f2bf(wv[j] - bf2f(g));
        }
        __syncthreads();
        *(int4*)&As_hi[sr * 40 + sc] = uh.v;
        *(int4*)&As_lo[sr * 40 + sc] = ul.v;
#pragma unroll
        for (int j = 0; j < 8; j++) {
            Bs_hi[(nc + j) * 40 + kr] = bh[j];
            Bs_lo[(nc + j) * 40 + kr] = bl[j];
        }
        __syncthreads();
        GEMM_FRAG_COMPUTE();
    }

#pragma unroll
    for (int mi = 0; mi < 2; mi++)
#pragma unroll
        for (int ni = 0; ni < 2; ni++) {
            int col = n0 + wn + ni * 16 + fr;
#pragma unroll
            for (int reg = 0; reg < 4; reg++) {
                int row = m0 + wm + mi * 16 + fq * 4 + reg;
                C[(size_t)row * N + col] = acc[mi][ni][reg];
            }
        }
}

// ---------------------------------------------------------------------------
// gemm2: xp = silu(conv(xz_x)) @ W_x[512,144].  A computed on the fly from xz
// (4-tap causal depthwise conv + bias + silu), B = W_x direct (transposed,
// guarded N=144).
// ---------------------------------------------------------------------------
__global__ __launch_bounds__(256) void gemm2_k(
    const float* __restrict__ xz, const float* __restrict__ Wf,
    const float* __restrict__ conv_w, const float* __restrict__ conv_b,
    float* __restrict__ C)
{
    const int N = 144, K = 512;
    __shared__ unsigned short As_hi[64 * 40], As_lo[64 * 40];
    __shared__ unsigned short Bs_hi[64 * 40], Bs_lo[64 * 40];

    const int t    = threadIdx.x;
    const int m0   = blockIdx.y * 64;
    const int n0   = blockIdx.x * 64;
    const int lane = t & 63;
    const int w    = t >> 6;
    const int wm   = (w >> 1) * 32;
    const int wn   = (w & 1) * 32;
    const int fr   = lane & 15;
    const int fq   = lane >> 4;

    const int sr = t >> 2, sc = (t & 3) * 8;
    const int kr = t >> 3, nc = (t & 7) * 8;

    const int r = m0 + sr;
    const int l = r % LSEQ;

    f32x4 acc[2][2] = {};

    for (int k0 = 0; k0 < K; k0 += 32) {
        const float* bp = xz + (size_t)r * 1024 + k0 + sc;
        float4 x0a = *(const float4*)(bp);
        float4 x0b = *(const float4*)(bp + 4);
        float4 x1a = make_float4(0,0,0,0), x1b = x1a, x2a = x1a, x2b = x1a, x3a = x1a, x3b = x1a;
        if (l >= 1) { x1a = *(const float4*)(bp - 1024); x1b = *(const float4*)(bp - 1020); }
        if (l >= 2) { x2a = *(const float4*)(bp - 2048); x2b = *(const float4*)(bp - 2044); }
        if (l >= 3) { x3a = *(const float4*)(bp - 3072); x3b = *(const float4*)(bp - 3068); }
        float x0[8] = {x0a.x,x0a.y,x0a.z,x0a.w,x0b.x,x0b.y,x0b.z,x0b.w};
        float x1[8] = {x1a.x,x1a.y,x1a.z,x1a.w,x1b.x,x1b.y,x1b.z,x1b.w};
        float x2[8] = {x2a.x,x2a.y,x2a.z,x2a.w,x2b.x,x2b.y,x2b.z,x2b.w};
        float x3[8] = {x3a.x,x3a.y,x3a.z,x3a.w,x3b.x,x3b.y,x3b.z,x3b.w};

        union { unsigned short us[8]; int4 v; } uh, ul;
#pragma unroll
        for (int j = 0; j < 8; j++) {
            int c = k0 + sc + j;
            float4 w4 = *(const float4*)(conv_w + c * 4);
            float a = conv_b[c];
            a = fmaf(x3[j], w4.x, a);
            a = fmaf(x2[j], w4.y, a);
            a = fmaf(x1[j], w4.z, a);
            a = fmaf(x0[j], w4.w, a);
            float s = siluf(a);
            unsigned short h = f2bf(s);
            uh.us[j] = h; ul.us[j] = f2bf(s - bf2f(h));
        }

        unsigned short bh[8], bl[8];
#pragma unroll
        for (int j = 0; j < 8; j++) {
            int colW = n0 + nc + j;
            float v = (colW < N) ? Wf[(size_t)(k0 + kr) * N + colW] : 0.f;
            unsigned short g = f2bf(v);
            bh[j] = g; bl[j] = f2bf(v - bf2f(g));
        }
        __syncthreads();
        *(int4*)&As_hi[sr * 40 + sc] = uh.v;
        *(int4*)&As_lo[sr * 40 + sc] = ul.v;
#pragma unroll
        for (int j = 0; j < 8; j++) {
            Bs_hi[(nc + j) * 40 + kr] = bh[j];
            Bs_lo[(nc + j) * 40 + kr] = bl[j];
        }
        __syncthreads();
        GEMM_FRAG_COMPUTE();
    }

#pragma unroll
    for (int mi = 0; mi < 2; mi++)
#pragma unroll
        for (int ni = 0; ni < 2; ni++) {
            int col = n0 + wn + ni * 16 + fr;
            if (col < N) {
#pragma unroll
                for (int reg = 0; reg < 4; reg++) {
                    int row = m0 + wm + mi * 16 + fq * 4 + reg;
                    C[(size_t)row * N + col] = acc[mi][ni][reg];
                }
            }
        }
}

// ---------------------------------------------------------------------------
// dtq_k (merged with pack_bc): conv/silu recomputed for u; writes
//   dt2[b][d][l] = (dt, dt*u)      gz2[b][d][l] = (u, silu(z))
//   bcq[b][lblk][n][t][2] = (B, C+phase)   (blockIdx.y==0 blocks only)
// ---------------------------------------------------------------------------
__global__ __launch_bounds__(256) void dtq_k(
    const float* __restrict__ xp, const float* __restrict__ W_dt,
    const float* __restrict__ b_dt, const float* __restrict__ dmag,
    const float* __restrict__ xz,
    const float* __restrict__ conv_w, const float* __restrict__ conv_b,
    const float* __restrict__ cosp, const float* __restrict__ sinp,
    const float* __restrict__ W_phase,
    float2* __restrict__ dt2, float2* __restrict__ gz2, float* __restrict__ bcq)
{
    const int b   = blockIdx.z;
    const int dt0 = blockIdx.y * 64;
    const int lt0 = blockIdx.x * 32;
    const int t   = threadIdx.x;

    __shared__ float Wl[16][64];
    __shared__ float xr[32][17];
    __shared__ float sc[32];
    __shared__ float xmu[32][64];
    __shared__ float xzs[32][64];

#pragma unroll
    for (int e = 0; e < 4; e++) {
        int idx = t + 256 * e;
        int i = idx >> 6, j = idx & 63;
        Wl[i][j] = W_dt[i * 512 + dt0 + j];
    }
#pragma unroll
    for (int e = 0; e < 2; e++) {
        int idx = t + 256 * e;
        int ll = idx >> 4, i = idx & 15;
        int l = lt0 + ll;
        xr[ll][i] = (l < LSEQ) ? xp[((size_t)(b * LSEQ + l)) * 144 + i] : 0.f;
    }
    if (t < 32) {
        int l = lt0 + t;
        float dm = 0.f;
        if (l < LSEQ) {
#pragma unroll
            for (int j = 0; j < 4; j++) dm += dmag[(b * 4 + j) * LSEQ + l];
        }
        sc[t] = 1.f + softplusf(dm * 0.25f);
    }
#pragma unroll
    for (int e = 0; e < 8; e++) {
        int idx = t + 256 * e;
        int ll = idx >> 6, dj = idx & 63;
        int l = lt0 + ll;
        float uu = 0.f, zz = 0.f;
        if (l < LSEQ) {
            int c = dt0 + dj;
            const float* base = xz + ((size_t)(b * LSEQ + l)) * 1024 + c;
            float4 w4 = *(const float4*)(conv_w + c * 4);
            float a = conv_b[c];
            if (l >= 3) a = fmaf(base[-3 * 1024], w4.x, a);
            if (l >= 2) a = fmaf(base[-2 * 1024], w4.y, a);
            if (l >= 1) a = fmaf(base[-1 * 1024], w4.z, a);
            a = fmaf(base[0], w4.w, a);
            uu = siluf(a);
            zz = base[512];
        }
        xmu[ll][dj] = uu;
        xzs[ll][dj] = zz;
    }
    __syncthreads();

    const int ll = t & 31;
    const int l  = lt0 + ll;
#pragma unroll
    for (int e = 0; e < 8; e++) {
        int dl = (t >> 5) * 8 + e;
        float acc = b_dt[dt0 + dl];
#pragma unroll
        for (int i = 0; i < 16; i++)
            acc = fmaf(xr[ll][i], Wl[i][dl], acc);
        float dtv = softplusf(acc) * sc[ll];
        float uu  = xmu[ll][dl];
        float sz  = siluf(xzs[ll][dl]);
        if (l < LSEQ) {
            size_t o = ((size_t)(b * 512 + dt0 + dl)) * LSEQ + l;
            dt2[o] = make_float2(dtv, dtv * uu);
            gz2[o] = make_float2(uu, sz);
        }
    }

    if (dt0 == 0) {
#pragma unroll
        for (int e = 0; e < 8; e++) {
            int idx = t + 256 * e;             // 0..2047
            int pll = idx >> 6, n = idx & 63;
            int pl  = lt0 + pll;
            if (pl < LSEQ) {
                int r = b * LSEQ + pl;
                float acc = 0.f;
#pragma unroll
                for (int j = 0; j < 4; j++) {
                    float cp = cosp[(b * 4 + j) * LSEQ + pl];
                    float sp = sinp[(b * 4 + j) * LSEQ + pl];
                    acc = fmaf(cp, W_phase[j * 64 + n], acc);
                    acc = fmaf(sp, W_phase[(4 + j) * 64 + n], acc);
                }
                float Bv = xp[(size_t)r * 144 + 16 + n];
                float Cv = xp[(size_t)r * 144 + 80 + n] + acc;
                size_t o = ((((size_t)b * 25 + (pl >> 3)) * 64 + n) * 8 + (pl & 7)) * 2;
                *(float2*)&bcq[o] = make_float2(Bv, Cv);
            }
        }
    }
}

// ---------------------------------------------------------------------------
// Selective scan (round-8 verified): one wave per (b,d), lane = state n.
// T=8 steps/chunk, ping-pong double buffer, deferred reduce-scatter butterfly;
// stores the RAW reduced sum (gating applied in gemm3 staging).
// ---------------------------------------------------------------------------
#define LOAD_CHUNK(BCV, DQV, LB) do {                                          \
    _Pragma("unroll")                                                          \
    for (int i = 0; i < 4; i++)                                                \
        BCV[i] = *(const float4*)(bcb + (size_t)(LB) * 1024 + i * 4);          \
    _Pragma("unroll")                                                          \
    for (int tt = 0; tt < 8; tt++) DQV[tt] = dqp[(LB) * 8 + tt];               \
} while (0)

#define SCAN_CHUNK(BCV, DQV, L0) do {                                          \
    float p[8];                                                                \
    _Pragma("unroll")                                                          \
    for (int tt = 0; tt < 8; tt++) {                                           \
        float Bv = (tt & 1) ? BCV[tt >> 1].z : BCV[tt >> 1].x;                 \
        float Cv = (tt & 1) ? BCV[tt >> 1].w : BCV[tt >> 1].y;                 \
        float e = __expf(DQV[tt].x * A);                                       \
        h = fmaf(e, h, DQV[tt].y * Bv);                                        \
        p[tt] = h * Cv;                                                        \
    }                                                                          \
    float q[4];                                                                \
    _Pragma("unroll")                                                          \
    for (int i = 0; i < 4; i++) {                                              \
        float keep = lo32 ? p[i] : p[i + 4];                                   \
        float send = lo32 ? p[i + 4] : p[i];                                   \
        q[i] = keep + __shfl_xor(send, 32, 64);                                \
    }                                                                          \
    float r2[2];                                                               \
    _Pragma("unroll")                                                          \
    for (int i = 0; i < 2; i++) {                                              \
        float keep = lo16 ? q[i] : q[i + 2];                                   \
        float send = lo16 ? q[i + 2] : q[i];                                   \
        r2[i] = keep + __shfl_xor(send, 16, 64);                               \
    }                                                                          \
    float keep8 = lo8 ? r2[0] : r2[1];                                         \
    float send8 = lo8 ? r2[1] : r2[0];                                         \
    float s = keep8 + __shfl_xor(send8, 8, 64);                                \
    s += __shfl_xor(s, 4, 64);                                                 \
    s += __shfl_xor(s, 2, 64);                                                 \
    s += __shfl_xor(s, 1, 64);                                                 \
    if (store_lane) yp[(L0) + tsel] = s;                                       \
} while (0)

__global__ __launch_bounds__(256, 4) void scan_k(
    const float2* __restrict__ dt2, const float* __restrict__ bcq,
    const float* __restrict__ A_log, float* __restrict__ y2)
{
    int wv0  = blockIdx.x * 4 + (threadIdx.x >> 6);      // 0..4095
    int wv   = __builtin_amdgcn_readfirstlane(wv0);
    int lane = threadIdx.x & 63;
    int b = wv >> 9;
    int d = wv & 511;

    float A = -__expf(A_log[d * 64 + lane]);

    const float2* dqp = dt2 + (size_t)(b * 512 + d) * LSEQ;
    const float*  bcb = bcq + ((size_t)b * 25 * 64 + lane) * 16;
    float*        yp  = y2  + (size_t)(b * 512 + d) * LSEQ;

    const bool lo32 = (lane & 32) == 0;
    const bool lo16 = (lane & 16) == 0;
    const bool lo8  = (lane & 8)  == 0;
    const bool store_lane = (lane & 7) == 0;
    const int  tsel = lane >> 3;

    float4 bc0[4], bc1[4];
    float2 dq0[8], dq1[8];
    LOAD_CHUNK(bc0, dq0, 0);

    float h = 0.f;
    for (int it = 0; it < 12; ++it) {        // chunks 0..23 (l = 0..191)
        LOAD_CHUNK(bc1, dq1, 2 * it + 1);
        SCAN_CHUNK(bc0, dq0, 16 * it);
        LOAD_CHUNK(bc0, dq0, 2 * it + 2);    // it=11 loads chunk 24
        SCAN_CHUNK(bc1, dq1, 16 * it + 8);
    }
    SCAN_CHUNK(bc0, dq0, 192);               // chunk 24
}

// ---------------------------------------------------------------------------
// gemm3: outp = gate(y2) @ W_out[512,256] + x.  A built in staging from
// d-major y2/gz2 (gate + split + transpose-scatter), B = W_out direct.
// ---------------------------------------------------------------------------
__global__ __launch_bounds__(256) void gemm3_k(
    const float* __restrict__ y2, const float2* __restrict__ gz2,
    const float* __restrict__ D_skip, const float* __restrict__ Wf,
    const float* __restrict__ resid, float* __restrict__ C)
{
    const int N = 256, K = 512;
    __shared__ unsigned short As_hi[64 * 40], As_lo[64 * 40];
    __shared__ unsigned short Bs_hi[64 * 40], Bs_lo[64 * 40];

    const int t    = threadIdx.x;
    const int m0   = blockIdx.y * 64;
    const int n0   = blockIdx.x * 64;
    const int lane = t & 63;
    const int w    = t >> 6;
    const int wm   = (w >> 1) * 32;
    const int wn   = (w & 1) * 32;
    const int fr   = lane & 15;
    const int fq   = lane >> 4;

    const int dr = t >> 3;           // 0..31: k-local (channel d)
    const int lc = (t & 7) * 8;      // 0..56: row-local base
    const int kr = t >> 3, nc = (t & 7) * 8;   // B staging (transpose)

    f32x4 acc[2][2] = {};

    for (int k0 = 0; k0 < K; k0 += 32) {
        int d = k0 + dr;
        float Dsk = D_skip[d];
        unsigned short hh[8], hl[8];
#pragma unroll
        for (int j = 0; j < 8; j++) {
            int r = m0 + lc + j;
            int bb = r / LSEQ;
            int l = r - bb * LSEQ;
            size_t o = ((size_t)(bb * 512 + d)) * LSEQ + l;
            float sv = y2[o];
            float2 g = gz2[o];
            float yv = (sv + g.x * Dsk) * g.y;
            unsigned short h = f2bf(yv);
            hh[j] = h; hl[j] = f2bf(yv - bf2f(h));
        }
        unsigned short bh[8], bl[8];
#pragma unroll
        for (int j = 0; j < 8; j++) {
            float v = Wf[(size_t)(k0 + kr) * N + n0 + nc + j];
            unsigned short g = f2bf(v);
            bh[j] = g; bl[j] = f2bf(v - bf2f(g));
        }
        __syncthreads();
#pragma unroll
        for (int j = 0; j < 8; j++) {
            As_hi[(lc + j) * 40 + dr] = hh[j];
            As_lo[(lc + j) * 40 + dr] = hl[j];
            Bs_hi[(nc + j) * 40 + kr] = bh[j];
            Bs_lo[(nc + j) * 40 + kr] = bl[j];
        }
        __syncthreads();
        GEMM_FRAG_COMPUTE();
    }

#pragma unroll
    for (int mi = 0; mi < 2; mi++)
#pragma unroll
        for (int ni = 0; ni < 2; ni++) {
            int col = n0 + wn + ni * 16 + fr;
#pragma unroll
            for (int reg = 0; reg < 4; reg++) {
                int row = m0 + wm + mi * 16 + fq * 4 + reg;
                C[(size_t)row * N + col] = acc[mi][ni][reg] + resid[(size_t)row * N + col];
            }
        }
}

// ---------------------------------------------------------------------------
// LayerNorm over last dim (256) + gamma/beta, fp32 out
// ---------------------------------------------------------------------------
__global__ __launch_bounds__(256) void ln_k(
    const float* __restrict__ outp, const float* __restrict__ gamma,
    const float* __restrict__ beta, float* __restrict__ out)
{
    int r = blockIdx.x;
    int t = threadIdx.x;
    float v = outp[(size_t)r * 256 + t];
    float s = v, ss = v * v;
#pragma unroll
    for (int off = 32; off > 0; off >>= 1) {
        s  += __shfl_xor(s,  off, 64);
        ss += __shfl_xor(ss, off, 64);
    }
    __shared__ float red[8];
    int w = t >> 6;
    if ((t & 63) == 0) { red[w] = s; red[4 + w] = ss; }
    __syncthreads();
    s  = red[0] + red[1] + red[2] + red[3];
    ss = red[4] + red[5] + red[6] + red[7];
    float mu  = s * (1.f / 256.f);
    float var = ss * (1.f / 256.f) - mu * mu;
    if (var < 0.f) var = 0.f;
    float inv = rsqrtf(var + 1e-12f);
    float o = (v - mu) * inv * gamma[t] + beta[t];
    out[(size_t)r * 256 + t] = o;
}

// ---------------------------------------------------------------------------
extern "C" void kernel_launch(void* const* d_in, const int* in_sizes, int n_in,
                              void* d_out, int out_size, void* d_ws, size_t ws_size,
                              hipStream_t stream)
{
    const float* x       = (const float*)d_in[0];
    const float* cosp    = (const float*)d_in[1];
    const float* sinp    = (const float*)d_in[2];
    const float* dmag    = (const float*)d_in[3];
    const float* W_in    = (const float*)d_in[4];
    const float* conv_w  = (const float*)d_in[5];
    const float* conv_b  = (const float*)d_in[6];
    const float* W_x     = (const float*)d_in[7];
    const float* W_dt    = (const float*)d_in[8];
    const float* b_dt    = (const float*)d_in[9];
    const float* A_log   = (const float*)d_in[10];
    const float* D_skip  = (const float*)d_in[11];
    const float* W_out   = (const float*)d_in[12];
    const float* gamma   = (const float*)d_in[13];
    const float* beta    = (const float*)d_in[14];
    const float* W_phase = (const float*)d_in[15];
    float* out = (float*)d_out;

    char* ws = (char*)d_ws;
    float*  xz   = (float*)ws;  ws += (size_t)ROWS * 1024 * 4;
    float*  xp   = (float*)ws;  ws += (size_t)ROWS * 144 * 4;
    float*  bcq  = (float*)ws;  ws += (size_t)ROWS * 128 * 4;
    float2* dt2  = (float2*)ws; ws += (size_t)ROWS * 512 * 8;
    float2* gz2  = (float2*)ws; ws += (size_t)ROWS * 512 * 8;
    float*  y2   = (float*)ws;  ws += (size_t)ROWS * 512 * 4;
    float*  outp = (float*)ws;  ws += (size_t)ROWS * 256 * 4;

    dim3 blk(256);
    gemm1_k <<<dim3(16, 25),  blk, 0, stream>>>(x, W_in, xz);
    gemm2_k <<<dim3(3, 25),   blk, 0, stream>>>(xz, W_x, conv_w, conv_b, xp);
    dtq_k   <<<dim3(7, 8, 8), blk, 0, stream>>>(xp, W_dt, b_dt, dmag, xz,
                                                conv_w, conv_b, cosp, sinp, W_phase,
                                                dt2, gz2, bcq);
    scan_k  <<<dim3(1024),    blk, 0, stream>>>(dt2, bcq, A_log, y2);
    gemm3_k <<<dim3(4, 25),   blk, 0, stream>>>(y2, gz2, D_skip, W_out, x, outp);
    ln_k    <<<dim3(1600),    blk, 0, stream>>>(outp, gamma, beta, out);
}